// Round 10
// baseline (350.415 us; speedup 1.0000x reference)
//
#include <hip/hip_runtime.h>

#define BB 8
#define CC 256
#define HH 64
#define WW 64
#define RED 64
#define HW 4096   // HH*WW
#define AST 72    // xs bf16 row stride ([px][c] layout, 16B-aligned rows)
#define XST 40    // xst bf16 row stride ([c][px], 16B-aligned rows)
#define LSH 72    // bf16 LDS row stride (x1 / res planes in invol phase)
#define WLS 10    // wl f32 stride
#define MAGIC 0x5A6B7C8Du   // non-repeated-byte: immune to byte-pattern poison

typedef __attribute__((ext_vector_type(8))) short s8v;   // 8 bf16 (4 VGPRs)
typedef __attribute__((ext_vector_type(4))) float f4v;   // MFMA accumulator

__device__ __forceinline__ unsigned short f2bf(float f) {  // RNE f32->bf16
    unsigned u = __float_as_uint(f);
    u += 0x7fff + ((u >> 16) & 1);
    return (unsigned short)(u >> 16);
}
__device__ __forceinline__ float b2f(unsigned short u) {   // bf16->f32
    return __uint_as_float(((unsigned)u) << 16);
}
__device__ __forceinline__ void waitFlag(unsigned* p) {    // acquire spin
    while (__hip_atomic_load(p, __ATOMIC_ACQUIRE, __HIP_MEMORY_SCOPE_AGENT) != MAGIC)
        __builtin_amdgcn_s_sleep(2);
}

// ---- single fused kernel: wtf-build -> dw+kern-gen -> involution+dwconv2 ----
// R9 rationale: budget accounting across R3/R7/R8 pins inter-dispatch
// drain/ramp gaps at ~20-30us (invol+gaps stable ~62us while dw varied;
// neither kernel ever exceeded the 43us fill floor).  Kernel boundaries are
// replaced by a device-scope flag protocol (graph-capture-safe, unlike R1's
// hipLaunchCooperativeKernel which failed under capture):
//   * 1024 blocks, guaranteed co-resident: launch_bounds(256,4) => VGPR<=128
//     => 16 waves/CU => 4 blocks/CU x 256 CU = 1024.  LDS 26.4KB (<40KB cap).
//   * wtf producers = first 64 launch-order blocks (b==0, bx<64); they wait
//     on nothing -> no deadlock; everyone else spins on 64 wtf flags.
//   * per-batch completion: each dw block fences + sets its flag; invol
//     phase spins on its batch's 128 flags (parallel, t<128).
//   * MAGIC is not a repeated-byte word -> workspace re-poison (byte-pattern
//     fill, every iteration, covers flags) cannot alias it; stale-MAGIC
//     across graph-replay iterations is benign (wtf/x1g/kern deterministic).
// dw body = R8 verified (shuffle halo, LDS-transposed deferred x1g stores,
// consts staged); invol body = R8 verified (bf16 res), 2 planes per block.
// [R12/R13: two-barrier k-loop shape preserved; do not re-pipeline.]
__global__ __launch_bounds__(256, 4) void fused(const float* __restrict__ x,
                                                const float* __restrict__ w_in,
                                                const float* __restrict__ b_in,
                                                const float* __restrict__ w_red,
                                                const float* __restrict__ b_red,
                                                const float* __restrict__ w_span,  // [9][64]
                                                const float* __restrict__ b_span,
                                                const float* __restrict__ w_out,
                                                const float* __restrict__ b_out,
                                                float* __restrict__ out,
                                                float* __restrict__ kern,
                                                unsigned short* __restrict__ x1g,
                                                unsigned short* __restrict__ wtf,
                                                unsigned* __restrict__ flw,   // [64]
                                                unsigned* __restrict__ fld) { // [8][128]
    // regions (dw): [0,8448) xs|r_lds, [8448,13568) xst, [13568,23808) wl|part,
    //               [23808,26404) consts.  (invol): [0,9216) x1s, [9216,18432) res.
    alignas(16) __shared__ char smem[26448];
    unsigned short* xs  = (unsigned short*)smem;           // [32px][AST] bf16
    float* r_lds        = (float*)smem;                    // [64o][33] f32, aliases xs
    unsigned short* xst = (unsigned short*)(smem + 8448);  // [64c][XST] bf16
    float* wl           = (float*)(smem + 13568);          // [256c][10] w_in+b_in
    float* part         = (float*)(smem + 13568);          // [8og][9][32px], aliases wl
    float* ws_l         = (float*)(smem + 23808);          // [576] w_span
    float* br_l         = ws_l + 576;                      // [64] b_red
    float* bs_l         = br_l + 64;                       // [9] b_span

    const int t    = threadIdx.x;
    const int bx   = blockIdx.x;
    const int b    = blockIdx.y;

    // ---- phase 0: wtf build by first-64 launch-order blocks ----
    if (b == 0 && bx < 64) {
        int e = bx * 256 + t;
        int j = e & 7, l2 = (e >> 3) & 63, nt = (e >> 9) & 3, kbg = e >> 11;
        int o = nt * 16 + (l2 & 15);
        int c = kbg * 32 + ((l2 >> 4) & 3) * 8 + j;
        wtf[e] = f2bf(w_red[o * CC + c]);
        __threadfence();
        __syncthreads();
        if (t == 0)
            __hip_atomic_store(&flw[bx], MAGIC, __ATOMIC_RELEASE,
                               __HIP_MEMORY_SCOPE_AGENT);
    }

    // ---- dw phase (R8 verified body) ----
    const int band = bx & 7;                     // XCD band swizzle
    const int idx  = bx >> 3;                    // 0..15
    const int h    = band * 8 + (idx >> 1);
    const int wh   = idx & 1;                    // 32-px half of the row
    const int l  = t & 63;
    const int wv = t >> 6;                       // wave 0..3
    const int mt = wv & 1, nh = wv >> 1;
    const int m0 = mt << 4;
    const int q  = t & 7;                        // phase-A: 8 col-quads x 32 ch
    const int pl = q << 2;
    const int wg = (wh << 5) | pl;
    const int cr = t >> 3;                       // 0..31

    #pragma unroll
    for (int j = 0; j < 9; j++) {
        int i = j * 256 + t;
        wl[(i / 9) * WLS + (i % 9)] = w_in[i];
    }
    wl[t * WLS + 9] = b_in[t];
    ws_l[t]       = w_span[t];
    ws_l[256 + t] = w_span[256 + t];
    if (t < 64) { ws_l[512 + t] = w_span[512 + t]; br_l[t] = b_red[t]; }
    if (t < 9)  bs_l[t] = b_span[t];

    float4 pv[2][3]; float phal[2][3];

    auto loadX = [&](int c0) {
        #pragma unroll
        for (int s = 0; s < 2; s++) {
            const int cc = c0 + s * 32 + cr;
            const float* xp = x + ((size_t)(b * CC + cc)) * HW;
            #pragma unroll
            for (int ky = 0; ky < 3; ky++) {
                int hh = h + ky - 1;
                if (hh < 0 || hh >= HH) {
                    pv[s][ky] = make_float4(0.f, 0.f, 0.f, 0.f);
                    phal[s][ky] = 0.f;
                    continue;
                }
                const float* row = xp + hh * WW + wg;
                pv[s][ky] = *(const float4*)row;
                float hv = 0.f;
                if (q == 0) { if (wg > 0) hv = row[-1]; }
                else if (q == 7) { if (wg + 4 < WW) hv = row[4]; }
                phal[s][ky] = hv;
            }
        }
    };
    auto computeA = [&](int c0) {
        #pragma unroll
        for (int s = 0; s < 2; s++) {
            const int cl = s * 32 + cr;
            const int cc = c0 + cl;
            const float* wp = wl + cc * WLS;
            const float bb = wp[9];
            float4 a4 = make_float4(bb, bb, bb, bb);
            #pragma unroll
            for (int ky = 0; ky < 3; ky++) {
                float4 v = pv[s][ky];
                float lf = __shfl_up(v.w, 1);
                if (q == 0) lf = phal[s][ky];
                float rt = __shfl_down(v.x, 1);
                if (q == 7) rt = phal[s][ky];
                float k0 = wp[ky * 3 + 0], k1 = wp[ky * 3 + 1], k2 = wp[ky * 3 + 2];
                a4.x = fmaf(k0, lf,  a4.x); a4.y = fmaf(k0, v.x, a4.y);
                a4.z = fmaf(k0, v.y, a4.z); a4.w = fmaf(k0, v.z, a4.w);
                a4.x = fmaf(k1, v.x, a4.x); a4.y = fmaf(k1, v.y, a4.y);
                a4.z = fmaf(k1, v.z, a4.z); a4.w = fmaf(k1, v.w, a4.w);
                a4.x = fmaf(k2, v.y, a4.x); a4.y = fmaf(k2, v.z, a4.y);
                a4.z = fmaf(k2, v.w, a4.z); a4.w = fmaf(k2, rt,  a4.w);
            }
            ushort4 pk;
            pk.x = f2bf(a4.x); pk.y = f2bf(a4.y);
            pk.z = f2bf(a4.z); pk.w = f2bf(a4.w);
            xs[(pl + 0) * AST + cl] = pk.x;
            xs[(pl + 1) * AST + cl] = pk.y;
            xs[(pl + 2) * AST + cl] = pk.z;
            xs[(pl + 3) * AST + cl] = pk.w;
            *(ushort4*)&xst[cl * XST + pl] = pk;
        }
    };

    s8v bfr[2][2];
    auto loadB = [&](int k) {
        #pragma unroll
        for (int kb = 0; kb < 2; kb++)
            #pragma unroll
            for (int ntl = 0; ntl < 2; ntl++) {
                int nt = (nh << 1) + ntl;
                int kbg = (k << 1) + kb;
                bfr[kb][ntl] = *(const s8v*)(wtf + (((kbg * 4 + nt) * 64 + l) << 3));
            }
    };

    f4v acc[2] = {{0.f, 0.f, 0.f, 0.f}, {0.f, 0.f, 0.f, 0.f}};
    int4 x1r[4];
    const int c2  = t >> 2;
    const int px2 = (t & 3) << 3;

    loadX(0);
    if (t < 64) waitFlag(&flw[t]);               // wtf ready (producers wait on nothing)
    __syncthreads();                             // wl/consts staged + wtf visible
    loadB(0);
    for (int k = 0; k < 4; k++) {
        computeA(k << 6);
        if (k < 3) loadX((k + 1) << 6);
        __syncthreads();
        #pragma unroll
        for (int kb = 0; kb < 2; kb++) {
            const unsigned short* ap =
                xs + (m0 + (l & 15)) * AST + (kb << 5) + ((l >> 4) & 3) * 8;
            s8v av = *(const s8v*)ap;
            #pragma unroll
            for (int ntl = 0; ntl < 2; ntl++)
                acc[ntl] = __builtin_amdgcn_mfma_f32_16x16x32_bf16(
                    av, bfr[kb][ntl], acc[ntl], 0, 0, 0);
        }
        x1r[k] = *(const int4*)&xst[c2 * XST + px2];
        if (k < 3) loadB(k + 1);
        __syncthreads();
    }

    #pragma unroll
    for (int ntl = 0; ntl < 2; ntl++) {
        int o = ((nh << 1) + ntl) * 16 + (l & 15);
        int pxr = m0 + ((l >> 4) & 3) * 4;
        #pragma unroll
        for (int i = 0; i < 4; i++)
            r_lds[o * 33 + pxr + i] = acc[ntl][i];
    }
    __syncthreads();

    const int px = t & 31;
    const int og = t >> 5;
    const int o0 = og << 3;
    float kk[9];
    #pragma unroll
    for (int j = 0; j < 9; j++) kk[j] = 0.f;
    #pragma unroll
    for (int i = 0; i < 8; i++) {
        float r = fmaxf(r_lds[(o0 + i) * 33 + px] + br_l[o0 + i], 0.f);
        #pragma unroll
        for (int j = 0; j < 9; j++) kk[j] = fmaf(ws_l[j * 64 + o0 + i], r, kk[j]);
    }
    __syncthreads();
    #pragma unroll
    for (int j = 0; j < 9; j++) part[(og * 9 + j) * 32 + px] = kk[j];
    __syncthreads();

    float* kp = kern + (size_t)b * 9 * HW + h * WW + (wh << 5) + px;
    const int jj = t >> 5;
    {
        float s = bs_l[jj];
        #pragma unroll
        for (int g = 0; g < 8; g++) s += part[(g * 9 + jj) * 32 + px];
        kp[jj * HW] = s;
    }
    if (t < 32) {
        float s = bs_l[8];
        #pragma unroll
        for (int g = 0; g < 8; g++) s += part[(g * 9 + 8) * 32 + px];
        kp[8 * HW] = s;
    }

    #pragma unroll
    for (int k = 0; k < 4; k++) {                // deferred x1g: full-line stores
        unsigned short* dst = x1g + ((size_t)(b * CC + (k << 6) + c2)) * HW
                            + h * WW + (wh << 5) + px2;
        *(int4*)dst = x1r[k];
    }

    // ---- publish: this block's kern rows + x1g rows are done ----
    __threadfence();                             // each thread's stores device-visible
    __syncthreads();                             // all threads fenced
    if (t == 0)
        __hip_atomic_store(&fld[b * 128 + bx], MAGIC, __ATOMIC_RELEASE,
                           __HIP_MEMORY_SCOPE_AGENT);

    // ---- wait for whole batch b (128 blocks), then involution phase ----
    if (t < 128) waitFlag(&fld[b * 128 + t]);
    __syncthreads();                             // batch data visible; LDS reusable

    unsigned short* x1s = (unsigned short*)smem;           // [64][LSH] bf16
    unsigned short* res = (unsigned short*)(smem + 9216);  // [64][LSH] bf16
    const int qi  = t & 15;
    const int w0i = qi << 2;
    const int ri  = t >> 4;                      // 0..15
    const float* kpb = kern + (size_t)b * 9 * HW;

    for (int p = 0; p < 2; p++) {
        const int c = (bx << 1) | p;

        {   // stage x1 plane (4096 bf16, contiguous)
            const unsigned short* xp = x1g + ((size_t)(b * CC + c)) * HW;
            const int hl = t >> 2;
            const int wl2 = (t & 3) << 4;
            *(s8v*)&x1s[hl * LSH + wl2]     = *(const s8v*)(xp + hl * WW + wl2);
            *(s8v*)&x1s[hl * LSH + wl2 + 8] = *(const s8v*)(xp + hl * WW + wl2 + 8);
        }
        __syncthreads();

        #pragma unroll
        for (int i = 0; i < 4; i++) {
            int hq = ri + (i << 4);
            int hw = hq * WW + w0i;
            float4 a = make_float4(0.f, 0.f, 0.f, 0.f);
            #pragma unroll
            for (int ky = 0; ky < 3; ky++) {
                int hh = hq + ky - 1;
                if (hh < 0 || hh >= HH) continue;
                const unsigned short* row = &x1s[hh * LSH + w0i];
                float vx = b2f(row[0]), vy = b2f(row[1]);
                float vz = b2f(row[2]), vw = b2f(row[3]);
                float lf = (w0i > 0)      ? b2f(row[-1]) : 0.f;
                float rt = (w0i + 4 < WW) ? b2f(row[4])  : 0.f;
                float4 k0 = *(const float4*)(kpb + (ky * 3 + 0) * HW + hw);
                float4 k1 = *(const float4*)(kpb + (ky * 3 + 1) * HW + hw);
                float4 k2 = *(const float4*)(kpb + (ky * 3 + 2) * HW + hw);
                a.x = fmaf(k0.x, lf, a.x); a.y = fmaf(k0.y, vx, a.y);
                a.z = fmaf(k0.z, vy, a.z); a.w = fmaf(k0.w, vz, a.w);
                a.x = fmaf(k1.x, vx, a.x); a.y = fmaf(k1.y, vy, a.y);
                a.z = fmaf(k1.z, vz, a.z); a.w = fmaf(k1.w, vw, a.w);
                a.x = fmaf(k2.x, vy, a.x); a.y = fmaf(k2.y, vz, a.y);
                a.z = fmaf(k2.z, vw, a.z); a.w = fmaf(k2.w, rt, a.w);
            }
            ushort4 pk;
            pk.x = f2bf(a.x); pk.y = f2bf(a.y);
            pk.z = f2bf(a.z); pk.w = f2bf(a.w);
            *(ushort4*)&res[hq * LSH + w0i] = pk;
        }
        __syncthreads();

        const float* wp = w_out + c * 9;
        const float bb = b_out[c];
        float* op = out + ((size_t)(b * CC + c)) * HW;
        #pragma unroll
        for (int i = 0; i < 4; i++) {
            int hq = ri + (i << 4);
            float4 a = make_float4(bb, bb, bb, bb);
            #pragma unroll
            for (int ky = 0; ky < 3; ky++) {
                int hh = hq + ky - 1;
                if (hh < 0 || hh >= HH) continue;
                const unsigned short* row = &res[hh * LSH + w0i];
                float vx = b2f(row[0]), vy = b2f(row[1]);
                float vz = b2f(row[2]), vw = b2f(row[3]);
                float lf = (w0i > 0)      ? b2f(row[-1]) : 0.f;
                float rt = (w0i + 4 < WW) ? b2f(row[4])  : 0.f;
                float k0 = wp[ky * 3 + 0], k1 = wp[ky * 3 + 1], k2 = wp[ky * 3 + 2];
                a.x = fmaf(k0, lf, a.x); a.y = fmaf(k0, vx, a.y);
                a.z = fmaf(k0, vy, a.z); a.w = fmaf(k0, vz, a.w);
                a.x = fmaf(k1, vx, a.x); a.y = fmaf(k1, vy, a.y);
                a.z = fmaf(k1, vz, a.z); a.w = fmaf(k1, vw, a.w);
                a.x = fmaf(k2, vy, a.x); a.y = fmaf(k2, vz, a.y);
                a.z = fmaf(k2, vw, a.z); a.w = fmaf(k2, rt, a.w);
            }
            *(float4*)(op + hq * WW + w0i) = a;
        }
        __syncthreads();                         // before next plane restages x1s
    }
}

extern "C" void kernel_launch(void* const* d_in, const int* in_sizes, int n_in,
                              void* d_out, int out_size, void* d_ws, size_t ws_size,
                              hipStream_t stream) {
    const float* x      = (const float*)d_in[0];
    const float* w_in   = (const float*)d_in[1];
    const float* b_in   = (const float*)d_in[2];
    const float* w_red  = (const float*)d_in[3];
    const float* b_red  = (const float*)d_in[4];
    const float* w_span = (const float*)d_in[5];
    const float* b_span = (const float*)d_in[6];
    const float* w_out  = (const float*)d_in[7];
    const float* b_out  = (const float*)d_in[8];
    float* out = (float*)d_out;

    float* kern = (float*)d_ws;                                   // 1.18 MB
    unsigned short* x1g = (unsigned short*)(kern + (size_t)BB * 9 * HW);  // 16.8 MB
    unsigned short* wtf = x1g + (size_t)BB * CC * HW;             // 32 KB
    unsigned* flw = (unsigned*)(wtf + 16384);                     // [64]
    unsigned* fld = flw + 64;                                     // [8][128]

    fused<<<dim3(128, BB), 256, 0, stream>>>(x, w_in, b_in, w_red, b_red,
                                             w_span, b_span, w_out, b_out,
                                             out, kern, x1g, wtf, flw, fld);
}

// Round 12
// 184.331 us; speedup vs baseline: 1.9010x; 1.9010x over previous
//
#include <hip/hip_runtime.h>

#define BB 8
#define CC 256
#define HH 64
#define WW 64
#define RED 64
#define HW 4096   // HH*WW
#define AST 72    // xs bf16 row stride ([px][c] layout, 16B-aligned rows)
#define LSF 68    // f32 LDS row stride (res plane in invol_dw)
#define LSH 72    // bf16 LDS row stride (x1 plane in invol_dw)

typedef __attribute__((ext_vector_type(8))) short s8v;   // 8 bf16 (4 VGPRs)
typedef __attribute__((ext_vector_type(4))) float f4v;   // MFMA accumulator

__device__ __forceinline__ unsigned short f2bf(float f) {  // RNE f32->bf16
    unsigned u = __float_as_uint(f);
    u += 0x7fff + ((u >> 16) & 1);
    return (unsigned short)(u >> 16);
}
__device__ __forceinline__ float b2f(unsigned short u) {   // bf16->f32
    return __uint_as_float(((unsigned)u) << 16);
}

// ---- fused dwconv1 + involution-kernel-generation (half-row blocks) ----
// R11: exact R4 geometry/bodies (best measured: 138.1us total), ONE change:
// build_wtf is deleted -- each thread builds its wave's 16 B-frags in
// REGISTERS in the prologue, straight from w_red (frag elem j is contiguous
// in c: 2 float4 L2 loads + 8 RNE cvt per frag; 32 loads total, one-time,
// hidden under loadX(0) latency).  Saves one dispatch + one boundary.
// [R10 lesson: intra-kernel device-scope flag sync costs ~200us on this
// chip (non-coherent per-XCD L2s; fence+poll traffic) -- kernel boundaries
// ARE the cheap global barrier.  R1: cooperative launch fails under graph
// capture.  Do not revisit either.]
// VGPR: +64 for bfrA -> ~100-120, under the 128 cap of launch_bounds(256,4)
// -> residency stays 4 blocks/CU.  k-loop force-unrolled so bfrA indexing
// is compile-time (runtime-indexed ext_vector arrays go to scratch).
// [R12/R13: two-barrier k-loop shape preserved; do not re-pipeline.]
__global__ __launch_bounds__(256, 4) void dw_kern(const float* __restrict__ x,
                                                  const float* __restrict__ w_in,
                                                  const float* __restrict__ b_in,
                                                  const float* __restrict__ w_red,
                                                  const float* __restrict__ b_red,
                                                  const float* __restrict__ w_span,  // [9][64]
                                                  const float* __restrict__ b_span,
                                                  float* __restrict__ kern,
                                                  unsigned short* __restrict__ x1g) {
    alignas(16) __shared__ char smem[8448 + 12288];      // 20.25 KB
    unsigned short* xs = (unsigned short*)smem;          // [32px][AST] bf16 (4.6 KB)
    float* r_lds = (float*)smem;                         // [64o][33] f32, aliases xs (dead)
    float* wl    = (float*)(smem + 8448);                // [256c][12] w_in+b_in staging
    float* part  = (float*)(smem + 8448);                // [8og][9][32px], aliases wl (dead)

    const int t    = threadIdx.x;
    const int bx   = blockIdx.x;
    const int band = bx & 7;                     // XCD band swizzle
    const int idx  = bx >> 3;                    // 0..15
    const int h    = band * 8 + (idx >> 1);      // 8 consecutive h per XCD band
    const int wh   = idx & 1;                    // which 32-px half of the row
    const int b    = blockIdx.y;
    const int l  = t & 63;                       // lane
    const int wv = t >> 6;                       // wave 0..3
    const int mt = wv & 1, nh = wv >> 1;
    const int m0 = mt << 4;
    // phase-A mapping: 8 col-quads x 32 channel-rows
    const int q  = t & 7;
    const int pl = q << 2;                       // local px 0..28
    const int wg = (wh << 5) | pl;               // global w 0..60
    const int cr = t >> 3;                       // 0..31

    // stage w_in [256][9] + b_in [256] -> wl[c*12 + {0..8, 9}] (one-time)
    #pragma unroll
    for (int j = 0; j < 9; j++) {
        int i = j * 256 + t;                     // coalesced read of 2304 floats
        wl[(i / 9) * 12 + (i % 9)] = w_in[i];
    }
    wl[t * 12 + 9] = b_in[t];

    float4 pv[2][3]; float plf[2][3], prt[2][3]; // x-row prefetch regs

    auto loadX = [&](int c0) {
        #pragma unroll
        for (int s = 0; s < 2; s++) {
            const int cc = c0 + s * 32 + cr;
            const float* xp = x + ((size_t)(b * CC + cc)) * HW;
            #pragma unroll
            for (int ky = 0; ky < 3; ky++) {
                int hh = h + ky - 1;
                if (hh < 0 || hh >= HH) {        // block-uniform branch
                    pv[s][ky] = make_float4(0.f, 0.f, 0.f, 0.f);
                    plf[s][ky] = 0.f; prt[s][ky] = 0.f;
                    continue;
                }
                const float* row = xp + hh * WW + wg;
                pv[s][ky]  = *(const float4*)row;
                plf[s][ky] = (wg > 0)      ? row[-1] : 0.f;
                prt[s][ky] = (wg + 4 < WW) ? row[4]  : 0.f;
            }
        }
    };
    auto computeA = [&](int c0) {                // dwconv from regs -> bf16 xs + x1g
        #pragma unroll
        for (int s = 0; s < 2; s++) {
            const int cl = s * 32 + cr;
            const int cc = c0 + cl;
            const float* wp = wl + cc * 12;      // weights from LDS (staged once)
            float4 wa = *(const float4*)wp;      // w0..w3
            float4 wb = *(const float4*)(wp + 4);// w4..w7
            float2 wc = *(const float2*)(wp + 8);// w8, bias
            float4 a4 = make_float4(wc.y, wc.y, wc.y, wc.y);
            const float kw[9] = {wa.x, wa.y, wa.z, wa.w, wb.x, wb.y, wb.z, wb.w, wc.x};
            #pragma unroll
            for (int ky = 0; ky < 3; ky++) {
                float4 v = pv[s][ky];
                float lf = plf[s][ky], rt = prt[s][ky];
                float k0 = kw[ky * 3 + 0], k1 = kw[ky * 3 + 1], k2 = kw[ky * 3 + 2];
                a4.x = fmaf(k0, lf,  a4.x); a4.y = fmaf(k0, v.x, a4.y);
                a4.z = fmaf(k0, v.y, a4.z); a4.w = fmaf(k0, v.z, a4.w);
                a4.x = fmaf(k1, v.x, a4.x); a4.y = fmaf(k1, v.y, a4.y);
                a4.z = fmaf(k1, v.z, a4.z); a4.w = fmaf(k1, v.w, a4.w);
                a4.x = fmaf(k2, v.y, a4.x); a4.y = fmaf(k2, v.z, a4.y);
                a4.z = fmaf(k2, v.w, a4.z); a4.w = fmaf(k2, rt,  a4.w);
            }
            ushort4 pk;
            pk.x = f2bf(a4.x); pk.y = f2bf(a4.y);
            pk.z = f2bf(a4.z); pk.w = f2bf(a4.w);
            xs[(pl + 0) * AST + cl] = pk.x;      // [px][c] for A-frag reads
            xs[(pl + 1) * AST + cl] = pk.y;
            xs[(pl + 2) * AST + cl] = pk.z;
            xs[(pl + 3) * AST + cl] = pk.w;
            // bf16 x1 handoff for kernel 2
            *(ushort4*)(x1g + ((size_t)(b * CC + cc)) * HW + h * WW + wg) = pk;
        }
    };

    // prologue B-frag build (replaces build_wtf + loadB): bfrA[kbg][ntl]
    // holds B[k][n] = w_red[o=n][c=k] for o = (2nh+ntl)*16 + (lane&15),
    // c = kbg*32 + ((lane>>4)&3)*8 + j.  16 frags = 64 VGPRs, read-only.
    s8v bfrA[8][2];
    loadX(0);                                    // issue x VMEM first
    #pragma unroll
    for (int kbg = 0; kbg < 8; kbg++)
        #pragma unroll
        for (int ntl = 0; ntl < 2; ntl++) {
            const int o   = (((nh << 1) + ntl) << 4) + (l & 15);
            const int c0b = (kbg << 5) + ((l >> 4) & 3) * 8;
            const float* wr = w_red + o * CC + c0b;
            float4 f0 = *(const float4*)wr;
            float4 f1 = *(const float4*)(wr + 4);
            s8v bv;
            bv[0] = (short)f2bf(f0.x); bv[1] = (short)f2bf(f0.y);
            bv[2] = (short)f2bf(f0.z); bv[3] = (short)f2bf(f0.w);
            bv[4] = (short)f2bf(f1.x); bv[5] = (short)f2bf(f1.y);
            bv[6] = (short)f2bf(f1.z); bv[7] = (short)f2bf(f1.w);
            bfrA[kbg][ntl] = bv;
        }

    f4v acc[2] = {{0.f, 0.f, 0.f, 0.f}, {0.f, 0.f, 0.f, 0.f}};

    __syncthreads();                             // wl staged before computeA reads it
    #pragma unroll                               // full unroll: bfrA indices static
    for (int k = 0; k < 4; k++) {
        computeA(k << 6);                        // regs -> xs (bf16) + x1g
        if (k < 3) loadX((k + 1) << 6);          // VMEM issue for next chunk
        __syncthreads();
        // phase B: 2 A-frag ds_read_b128 + 4 MFMA per wave
        #pragma unroll
        for (int kb = 0; kb < 2; kb++) {
            const unsigned short* ap =
                xs + (m0 + (l & 15)) * AST + (kb << 5) + ((l >> 4) & 3) * 8;
            s8v av = *(const s8v*)ap;
            #pragma unroll
            for (int ntl = 0; ntl < 2; ntl++)
                acc[ntl] = __builtin_amdgcn_mfma_f32_16x16x32_bf16(
                    av, bfrA[(k << 1) + kb][ntl], acc[ntl], 0, 0, 0);
        }
        __syncthreads();                         // xs consumed; safe to overwrite
    }

    // C-frags -> r_lds[o][33] (aliases dead xs); D row = px, col = o
    #pragma unroll
    for (int ntl = 0; ntl < 2; ntl++) {
        int o = ((nh << 1) + ntl) * 16 + (l & 15);
        int pxr = m0 + ((l >> 4) & 3) * 4;       // row = (lane>>4)*4 + i
        #pragma unroll
        for (int i = 0; i < 4; i++)
            r_lds[o * 33 + pxr + i] = acc[ntl][i];
    }
    __syncthreads();

    // epilogue: relu + span contraction; og = t>>5 (8 o-groups of 8)
    const int px = t & 31;
    const int og = t >> 5;
    const int o0 = og << 3;
    float kk[9];
    #pragma unroll
    for (int j = 0; j < 9; j++) kk[j] = 0.f;
    #pragma unroll
    for (int i = 0; i < 8; i++) {
        float r = fmaxf(r_lds[(o0 + i) * 33 + px] + b_red[o0 + i], 0.f);
        #pragma unroll
        for (int j = 0; j < 9; j++) kk[j] = fmaf(w_span[j * RED + o0 + i], r, kk[j]);
    }
    __syncthreads();                             // wl dead -> part may overwrite
    #pragma unroll
    for (int j = 0; j < 9; j++) part[(og * 9 + j) * 32 + px] = kk[j];
    __syncthreads();

    // cross-o-group reduction: thread (px, jj) sums 8 partials for kern[jj]
    float* kp = kern + (size_t)b * 9 * HW + h * WW + (wh << 5) + px;
    const int jj = t >> 5;                       // 0..7
    {
        float s = b_span[jj];
        #pragma unroll
        for (int g = 0; g < 8; g++) s += part[(g * 9 + jj) * 32 + px];
        kp[jj * HW] = s;
    }
    if (t < 32) {                                // j = 8 by lanes 0..31
        float s = b_span[8];
        #pragma unroll
        for (int g = 0; g < 8; g++) s += part[(g * 9 + 8) * 32 + px];
        kp[8 * HW] = s;
    }
}

// ---- involution-apply + dwconv2, consuming precomputed bf16 x1 ----
// [R4-exact -- part of the best measured 138.1us config.]  One block per
// (c,b) plane: 256 threads.  LDS 26.6 KB -> 6 blocks/CU.
__global__ __launch_bounds__(256) void invol_dw(const unsigned short* __restrict__ x1g,
                                                const float* __restrict__ kern,
                                                const float* __restrict__ w_out,
                                                const float* __restrict__ b_out,
                                                float* __restrict__ out) {
    __shared__ unsigned short x1s[HH * LSH];     // bf16 x1 plane (9.2 KB)
    __shared__ float res[HH * LSF];              // involution result (17.4 KB)
    const int t  = threadIdx.x;
    const int q  = t & 15;
    const int w0 = q << 2;
    const int r  = t >> 4;                       // 0..15
    const int c = blockIdx.x, b = blockIdx.y;

    // stage x1 plane: 4096 bf16, fully contiguous (16 shorts/thread)
    {
        const unsigned short* xp = x1g + ((size_t)(b * CC + c)) * HW;
        const int hl = t >> 2;                   // 0..63
        const int wl2 = (t & 3) << 4;            // 0,16,32,48
        *(s8v*)&x1s[hl * LSH + wl2]     = *(const s8v*)(xp + hl * WW + wl2);
        *(s8v*)&x1s[hl * LSH + wl2 + 8] = *(const s8v*)(xp + hl * WW + wl2 + 8);
    }
    __syncthreads();

    // involution apply: res[h,w] = sum_k kern[k,h,w] * x1[h+dy, w+dx]
    const float* kp = kern + (size_t)b * 9 * HW;
    #pragma unroll
    for (int i = 0; i < 4; i++) {
        int h  = r + (i << 4);
        int hw = h * WW + w0;
        float4 acc = make_float4(0.f, 0.f, 0.f, 0.f);
        #pragma unroll
        for (int ky = 0; ky < 3; ky++) {
            int hh = h + ky - 1;
            if (hh < 0 || hh >= HH) continue;    // zero patch -> zero contribution
            const unsigned short* row = &x1s[hh * LSH + w0];
            float vx = b2f(row[0]), vy = b2f(row[1]);
            float vz = b2f(row[2]), vw = b2f(row[3]);
            float lf = (w0 > 0)      ? b2f(row[-1]) : 0.f;
            float rt = (w0 + 4 < WW) ? b2f(row[4])  : 0.f;
            float4 k0 = *(const float4*)(kp + (ky * 3 + 0) * HW + hw);
            float4 k1 = *(const float4*)(kp + (ky * 3 + 1) * HW + hw);
            float4 k2 = *(const float4*)(kp + (ky * 3 + 2) * HW + hw);
            acc.x = fmaf(k0.x, lf, acc.x); acc.y = fmaf(k0.y, vx, acc.y);
            acc.z = fmaf(k0.z, vy, acc.z); acc.w = fmaf(k0.w, vz, acc.w);
            acc.x = fmaf(k1.x, vx, acc.x); acc.y = fmaf(k1.y, vy, acc.y);
            acc.z = fmaf(k1.z, vz, acc.z); acc.w = fmaf(k1.w, vw, acc.w);
            acc.x = fmaf(k2.x, vy, acc.x); acc.y = fmaf(k2.y, vz, acc.y);
            acc.z = fmaf(k2.z, vw, acc.z); acc.w = fmaf(k2.w, rt, acc.w);
        }
        *(float4*)&res[h * LSF + w0] = acc;
    }
    __syncthreads();

    // dwconv2 from res (f32 LDS), write final output
    const float* wp = w_out + c * 9;             // block-uniform -> s_load
    const float bb = b_out[c];
    float* op = out + ((size_t)(b * CC + c)) * HW;
    #pragma unroll
    for (int i = 0; i < 4; i++) {
        int h = r + (i << 4);
        float4 acc = make_float4(bb, bb, bb, bb);
        #pragma unroll
        for (int ky = 0; ky < 3; ky++) {
            int hh = h + ky - 1;
            if (hh < 0 || hh >= HH) continue;
            const float* row = &res[hh * LSF + w0];
            float4 v = *(const float4*)row;
            float lf = (w0 > 0)      ? row[-1] : 0.f;
            float rt = (w0 + 4 < WW) ? row[4]  : 0.f;
            float k0 = wp[ky * 3 + 0], k1 = wp[ky * 3 + 1], k2 = wp[ky * 3 + 2];
            acc.x = fmaf(k0, lf,  acc.x); acc.y = fmaf(k0, v.x, acc.y);
            acc.z = fmaf(k0, v.y, acc.z); acc.w = fmaf(k0, v.z, acc.w);
            acc.x = fmaf(k1, v.x, acc.x); acc.y = fmaf(k1, v.y, acc.y);
            acc.z = fmaf(k1, v.z, acc.z); acc.w = fmaf(k1, v.w, acc.w);
            acc.x = fmaf(k2, v.y, acc.x); acc.y = fmaf(k2, v.z, acc.y);
            acc.z = fmaf(k2, v.w, acc.z); acc.w = fmaf(k2, rt,  acc.w);
        }
        *(float4*)(op + h * WW + w0) = acc;
    }
}

extern "C" void kernel_launch(void* const* d_in, const int* in_sizes, int n_in,
                              void* d_out, int out_size, void* d_ws, size_t ws_size,
                              hipStream_t stream) {
    const float* x      = (const float*)d_in[0];
    const float* w_in   = (const float*)d_in[1];
    const float* b_in   = (const float*)d_in[2];
    const float* w_red  = (const float*)d_in[3];
    const float* b_red  = (const float*)d_in[4];
    const float* w_span = (const float*)d_in[5];
    const float* b_span = (const float*)d_in[6];
    const float* w_out  = (const float*)d_in[7];
    const float* b_out  = (const float*)d_in[8];
    float* out = (float*)d_out;

    float* kern = (float*)d_ws;                              // 1.18 MB
    unsigned short* x1g = (unsigned short*)(kern + (size_t)BB * 9 * HW); // 16.8 MB bf16

    dw_kern<<<dim3(128, BB), 256, 0, stream>>>(x, w_in, b_in, w_red, b_red,
                                               w_span, b_span, kern, x1g);
    invol_dw<<<dim3(CC, BB), 256, 0, stream>>>(x1g, kern, w_out, b_out, out);
}

// Round 13
// 140.326 us; speedup vs baseline: 2.4972x; 1.3136x over previous
//
#include <hip/hip_runtime.h>

#define BB 8
#define CC 256
#define HH 64
#define WW 64
#define RED 64
#define HW 4096   // HH*WW
#define AST 72    // xs bf16 row stride ([px][c] layout, 16B-aligned rows)
#define LSH 72    // bf16 LDS row stride (x1 / res planes in invol_dw)

typedef __attribute__((ext_vector_type(8))) short s8v;   // 8 bf16 (4 VGPRs)
typedef __attribute__((ext_vector_type(4))) float f4v;   // MFMA accumulator

__device__ __forceinline__ unsigned short f2bf(float f) {  // RNE f32->bf16
    unsigned u = __float_as_uint(f);
    u += 0x7fff + ((u >> 16) & 1);
    return (unsigned short)(u >> 16);
}
__device__ __forceinline__ float b2f(unsigned short u) {   // bf16->f32
    return __uint_as_float(((unsigned)u) << 16);
}

// ---- build w_red in B-fragment order (bf16) ----
// wtf[e], e = ((kbg*4 + nt)*64 + lane)*8 + j  holds  B[k][n] = w_red[o=n][c=k]
// with n = nt*16 + (lane&15), k = kbg*32 + (lane>>4)*8 + j.  32 KB, L2-resident.
// [R12 lesson: building these 16 frags in dw_kern REGISTERS spills (VGPR
// cap 128 at 4 blk/CU; VGPR_Count fell to 64, WRITE_SIZE 46->110MB, FETCH
// 27->68MB = scratch traffic, dw 76us).  The separate 2us kernel is cheap.]
__global__ __launch_bounds__(256) void build_wtf(const float* __restrict__ w_red,
                                                 unsigned short* __restrict__ wtf) {
    int e = blockIdx.x * 256 + threadIdx.x;      // 64 blocks -> 16384
    int j = e & 7, l = (e >> 3) & 63, nt = (e >> 9) & 3, kbg = e >> 11;
    int o = nt * 16 + (l & 15);
    int c = kbg * 32 + ((l >> 4) & 3) * 8 + j;
    wtf[e] = f2bf(w_red[o * CC + c]);
}

// ---- fused dwconv1 + involution-kernel-generation (half-row blocks) ----
// R4-EXACT body (best measured config: 138.1us total, dw ~28us by budget
// accounting).  256 threads / 4 waves, grid (128,8) -> 4 blocks/CU.
// w_in/b_in staged once into LDS; B-frags from pre-built wtf (1 s8v load
// each); two-barrier k-loop [R12/R13: do not re-pipeline].
// [R10: no intra-kernel device-scope sync -- costs ~200us on this chip.]
__global__ __launch_bounds__(256, 4) void dw_kern(const float* __restrict__ x,
                                                  const float* __restrict__ w_in,
                                                  const float* __restrict__ b_in,
                                                  const unsigned short* __restrict__ wtf,
                                                  const float* __restrict__ b_red,
                                                  const float* __restrict__ w_span,  // [9][64]
                                                  const float* __restrict__ b_span,
                                                  float* __restrict__ kern,
                                                  unsigned short* __restrict__ x1g) {
    alignas(16) __shared__ char smem[8448 + 12288];      // 20.25 KB
    unsigned short* xs = (unsigned short*)smem;          // [32px][AST] bf16 (4.6 KB)
    float* r_lds = (float*)smem;                         // [64o][33] f32, aliases xs (dead)
    float* wl    = (float*)(smem + 8448);                // [256c][12] w_in+b_in staging
    float* part  = (float*)(smem + 8448);                // [8og][9][32px], aliases wl (dead)

    const int t    = threadIdx.x;
    const int bx   = blockIdx.x;
    const int band = bx & 7;                     // XCD band swizzle
    const int idx  = bx >> 3;                    // 0..15
    const int h    = band * 8 + (idx >> 1);      // 8 consecutive h per XCD band
    const int wh   = idx & 1;                    // which 32-px half of the row
    const int b    = blockIdx.y;
    const int l  = t & 63;                       // lane
    const int wv = t >> 6;                       // wave 0..3
    const int mt = wv & 1, nh = wv >> 1;
    const int m0 = mt << 4;
    // phase-A mapping: 8 col-quads x 32 channel-rows
    const int q  = t & 7;
    const int pl = q << 2;                       // local px 0..28
    const int wg = (wh << 5) | pl;               // global w 0..60
    const int cr = t >> 3;                       // 0..31

    // stage w_in [256][9] + b_in [256] -> wl[c*12 + {0..8, 9}] (one-time)
    #pragma unroll
    for (int j = 0; j < 9; j++) {
        int i = j * 256 + t;                     // coalesced read of 2304 floats
        wl[(i / 9) * 12 + (i % 9)] = w_in[i];
    }
    wl[t * 12 + 9] = b_in[t];

    float4 pv[2][3]; float plf[2][3], prt[2][3]; // x-row prefetch regs

    auto loadX = [&](int c0) {
        #pragma unroll
        for (int s = 0; s < 2; s++) {
            const int cc = c0 + s * 32 + cr;
            const float* xp = x + ((size_t)(b * CC + cc)) * HW;
            #pragma unroll
            for (int ky = 0; ky < 3; ky++) {
                int hh = h + ky - 1;
                if (hh < 0 || hh >= HH) {        // block-uniform branch
                    pv[s][ky] = make_float4(0.f, 0.f, 0.f, 0.f);
                    plf[s][ky] = 0.f; prt[s][ky] = 0.f;
                    continue;
                }
                const float* row = xp + hh * WW + wg;
                pv[s][ky]  = *(const float4*)row;
                plf[s][ky] = (wg > 0)      ? row[-1] : 0.f;
                prt[s][ky] = (wg + 4 < WW) ? row[4]  : 0.f;
            }
        }
    };
    auto computeA = [&](int c0) {                // dwconv from regs -> bf16 xs + x1g
        #pragma unroll
        for (int s = 0; s < 2; s++) {
            const int cl = s * 32 + cr;
            const int cc = c0 + cl;
            const float* wp = wl + cc * 12;      // weights from LDS (staged once)
            float4 wa = *(const float4*)wp;      // w0..w3
            float4 wb = *(const float4*)(wp + 4);// w4..w7
            float2 wc = *(const float2*)(wp + 8);// w8, bias
            float4 a4 = make_float4(wc.y, wc.y, wc.y, wc.y);
            const float kw[9] = {wa.x, wa.y, wa.z, wa.w, wb.x, wb.y, wb.z, wb.w, wc.x};
            #pragma unroll
            for (int ky = 0; ky < 3; ky++) {
                float4 v = pv[s][ky];
                float lf = plf[s][ky], rt = prt[s][ky];
                float k0 = kw[ky * 3 + 0], k1 = kw[ky * 3 + 1], k2 = kw[ky * 3 + 2];
                a4.x = fmaf(k0, lf,  a4.x); a4.y = fmaf(k0, v.x, a4.y);
                a4.z = fmaf(k0, v.y, a4.z); a4.w = fmaf(k0, v.z, a4.w);
                a4.x = fmaf(k1, v.x, a4.x); a4.y = fmaf(k1, v.y, a4.y);
                a4.z = fmaf(k1, v.z, a4.z); a4.w = fmaf(k1, v.w, a4.w);
                a4.x = fmaf(k2, v.y, a4.x); a4.y = fmaf(k2, v.z, a4.y);
                a4.z = fmaf(k2, v.w, a4.z); a4.w = fmaf(k2, rt,  a4.w);
            }
            ushort4 pk;
            pk.x = f2bf(a4.x); pk.y = f2bf(a4.y);
            pk.z = f2bf(a4.z); pk.w = f2bf(a4.w);
            xs[(pl + 0) * AST + cl] = pk.x;      // [px][c] for A-frag reads
            xs[(pl + 1) * AST + cl] = pk.y;
            xs[(pl + 2) * AST + cl] = pk.z;
            xs[(pl + 3) * AST + cl] = pk.w;
            // bf16 x1 handoff for kernel 2
            *(ushort4*)(x1g + ((size_t)(b * CC + cc)) * HW + h * WW + wg) = pk;
        }
    };

    s8v bfr[2][2];                               // B-frags [kb][ntl] for current chunk
    auto loadB = [&](int k) {
        #pragma unroll
        for (int kb = 0; kb < 2; kb++)
            #pragma unroll
            for (int ntl = 0; ntl < 2; ntl++) {
                int nt = (nh << 1) + ntl;
                int kbg = (k << 1) + kb;
                bfr[kb][ntl] = *(const s8v*)(wtf + (((kbg * 4 + nt) * 64 + l) << 3));
            }
    };

    f4v acc[2] = {{0.f, 0.f, 0.f, 0.f}, {0.f, 0.f, 0.f, 0.f}};

    loadX(0); loadB(0);
    __syncthreads();                             // wl staged before computeA reads it
    for (int k = 0; k < 4; k++) {
        computeA(k << 6);                        // regs -> xs (bf16) + x1g
        if (k < 3) loadX((k + 1) << 6);          // VMEM issue for next chunk
        __syncthreads();
        // phase B: 2 A-frag ds_read_b128 + 4 MFMA per wave
        #pragma unroll
        for (int kb = 0; kb < 2; kb++) {
            const unsigned short* ap =
                xs + (m0 + (l & 15)) * AST + (kb << 5) + ((l >> 4) & 3) * 8;
            s8v av = *(const s8v*)ap;
            #pragma unroll
            for (int ntl = 0; ntl < 2; ntl++)
                acc[ntl] = __builtin_amdgcn_mfma_f32_16x16x32_bf16(
                    av, bfr[kb][ntl], acc[ntl], 0, 0, 0);
        }
        if (k < 3) loadB(k + 1);
        __syncthreads();                         // xs consumed; safe to overwrite
    }

    // C-frags -> r_lds[o][33] (aliases dead xs); D row = px, col = o
    #pragma unroll
    for (int ntl = 0; ntl < 2; ntl++) {
        int o = ((nh << 1) + ntl) * 16 + (l & 15);
        int pxr = m0 + ((l >> 4) & 3) * 4;       // row = (lane>>4)*4 + i
        #pragma unroll
        for (int i = 0; i < 4; i++)
            r_lds[o * 33 + pxr + i] = acc[ntl][i];
    }
    __syncthreads();

    // epilogue: relu + span contraction; og = t>>5 (8 o-groups of 8)
    const int px = t & 31;
    const int og = t >> 5;
    const int o0 = og << 3;
    float kk[9];
    #pragma unroll
    for (int j = 0; j < 9; j++) kk[j] = 0.f;
    #pragma unroll
    for (int i = 0; i < 8; i++) {
        float r = fmaxf(r_lds[(o0 + i) * 33 + px] + b_red[o0 + i], 0.f);
        #pragma unroll
        for (int j = 0; j < 9; j++) kk[j] = fmaf(w_span[j * RED + o0 + i], r, kk[j]);
    }
    __syncthreads();                             // wl dead -> part may overwrite
    #pragma unroll
    for (int j = 0; j < 9; j++) part[(og * 9 + j) * 32 + px] = kk[j];
    __syncthreads();

    // cross-o-group reduction: thread (px, jj) sums 8 partials for kern[jj]
    float* kp = kern + (size_t)b * 9 * HW + h * WW + (wh << 5) + px;
    const int jj = t >> 5;                       // 0..7
    {
        float s = b_span[jj];
        #pragma unroll
        for (int g = 0; g < 8; g++) s += part[(g * 9 + jj) * 32 + px];
        kp[jj * HW] = s;
    }
    if (t < 32) {                                // j = 8 by lanes 0..31
        float s = b_span[8];
        #pragma unroll
        for (int g = 0; g < 8; g++) s += part[(g * 9 + 8) * 32 + px];
        kp[8 * HW] = s;
    }
}

// ---- involution-apply + dwconv2, consuming precomputed bf16 x1 ----
// R13 change vs R4: res plane bf16 -> LDS 18.4 KB -> 8 blocks/CU (was 6).
// Grid is 2048 = 8/CU, so 8-resident turns the 6+2 two-round schedule with
// tail into EXACTLY one round.  bf16-res variant correctness-verified in
// R7/R8/R10 benches (absmax identical 9.77e-4).
__global__ __launch_bounds__(256, 8) void invol_dw(const unsigned short* __restrict__ x1g,
                                                   const float* __restrict__ kern,
                                                   const float* __restrict__ w_out,
                                                   const float* __restrict__ b_out,
                                                   float* __restrict__ out) {
    __shared__ unsigned short x1s[HH * LSH];     // bf16 x1 plane (9.2 KB)
    __shared__ unsigned short res[HH * LSH];     // bf16 involution result (9.2 KB)
    const int t  = threadIdx.x;
    const int q  = t & 15;
    const int w0 = q << 2;
    const int r  = t >> 4;                       // 0..15
    const int c = blockIdx.x, b = blockIdx.y;

    // stage x1 plane: 4096 bf16, fully contiguous (16 shorts/thread)
    {
        const unsigned short* xp = x1g + ((size_t)(b * CC + c)) * HW;
        const int hl = t >> 2;                   // 0..63
        const int wl2 = (t & 3) << 4;            // 0,16,32,48
        *(s8v*)&x1s[hl * LSH + wl2]     = *(const s8v*)(xp + hl * WW + wl2);
        *(s8v*)&x1s[hl * LSH + wl2 + 8] = *(const s8v*)(xp + hl * WW + wl2 + 8);
    }
    __syncthreads();

    // involution apply: res[h,w] = sum_k kern[k,h,w] * x1[h+dy, w+dx]
    const float* kp = kern + (size_t)b * 9 * HW;
    #pragma unroll
    for (int i = 0; i < 4; i++) {
        int h  = r + (i << 4);
        int hw = h * WW + w0;
        float4 acc = make_float4(0.f, 0.f, 0.f, 0.f);
        #pragma unroll
        for (int ky = 0; ky < 3; ky++) {
            int hh = h + ky - 1;
            if (hh < 0 || hh >= HH) continue;
            const unsigned short* row = &x1s[hh * LSH + w0];
            float vx = b2f(row[0]), vy = b2f(row[1]);
            float vz = b2f(row[2]), vw = b2f(row[3]);
            float lf = (w0 > 0)      ? b2f(row[-1]) : 0.f;
            float rt = (w0 + 4 < WW) ? b2f(row[4])  : 0.f;
            float4 k0 = *(const float4*)(kp + (ky * 3 + 0) * HW + hw);
            float4 k1 = *(const float4*)(kp + (ky * 3 + 1) * HW + hw);
            float4 k2 = *(const float4*)(kp + (ky * 3 + 2) * HW + hw);
            acc.x = fmaf(k0.x, lf, acc.x); acc.y = fmaf(k0.y, vx, acc.y);
            acc.z = fmaf(k0.z, vy, acc.z); acc.w = fmaf(k0.w, vz, acc.w);
            acc.x = fmaf(k1.x, vx, acc.x); acc.y = fmaf(k1.y, vy, acc.y);
            acc.z = fmaf(k1.z, vz, acc.z); acc.w = fmaf(k1.w, vw, acc.w);
            acc.x = fmaf(k2.x, vy, acc.x); acc.y = fmaf(k2.y, vz, acc.y);
            acc.z = fmaf(k2.z, vw, acc.z); acc.w = fmaf(k2.w, rt, acc.w);
        }
        ushort4 pk;
        pk.x = f2bf(acc.x); pk.y = f2bf(acc.y);
        pk.z = f2bf(acc.z); pk.w = f2bf(acc.w);
        *(ushort4*)&res[h * LSH + w0] = pk;      // bf16 res
    }
    __syncthreads();

    // dwconv2 from res (bf16 LDS), write final output
    const float* wp = w_out + c * 9;             // block-uniform -> s_load
    const float bb = b_out[c];
    float* op = out + ((size_t)(b * CC + c)) * HW;
    #pragma unroll
    for (int i = 0; i < 4; i++) {
        int h = r + (i << 4);
        float4 acc = make_float4(bb, bb, bb, bb);
        #pragma unroll
        for (int ky = 0; ky < 3; ky++) {
            int hh = h + ky - 1;
            if (hh < 0 || hh >= HH) continue;
            const unsigned short* row = &res[hh * LSH + w0];
            float vx = b2f(row[0]), vy = b2f(row[1]);
            float vz = b2f(row[2]), vw = b2f(row[3]);
            float lf = (w0 > 0)      ? b2f(row[-1]) : 0.f;
            float rt = (w0 + 4 < WW) ? b2f(row[4])  : 0.f;
            float k0 = wp[ky * 3 + 0], k1 = wp[ky * 3 + 1], k2 = wp[ky * 3 + 2];
            acc.x = fmaf(k0, lf, acc.x); acc.y = fmaf(k0, vx, acc.y);
            acc.z = fmaf(k0, vy, acc.z); acc.w = fmaf(k0, vz, acc.w);
            acc.x = fmaf(k1, vx, acc.x); acc.y = fmaf(k1, vy, acc.y);
            acc.z = fmaf(k1, vz, acc.z); acc.w = fmaf(k1, vw, acc.w);
            acc.x = fmaf(k2, vy, acc.x); acc.y = fmaf(k2, vz, acc.y);
            acc.z = fmaf(k2, vw, acc.z); acc.w = fmaf(k2, rt, acc.w);
        }
        *(float4*)(op + h * WW + w0) = acc;
    }
}

extern "C" void kernel_launch(void* const* d_in, const int* in_sizes, int n_in,
                              void* d_out, int out_size, void* d_ws, size_t ws_size,
                              hipStream_t stream) {
    const float* x      = (const float*)d_in[0];
    const float* w_in   = (const float*)d_in[1];
    const float* b_in   = (const float*)d_in[2];
    const float* w_red  = (const float*)d_in[3];
    const float* b_red  = (const float*)d_in[4];
    const float* w_span = (const float*)d_in[5];
    const float* b_span = (const float*)d_in[6];
    const float* w_out  = (const float*)d_in[7];
    const float* b_out  = (const float*)d_in[8];
    float* out = (float*)d_out;

    float* kern = (float*)d_ws;                              // 1.18 MB
    unsigned short* x1g = (unsigned short*)(kern + (size_t)BB * 9 * HW); // 16.8 MB bf16
    unsigned short* wtf = x1g + (size_t)BB * CC * HW;        // 32 KB bf16

    build_wtf<<<64, 256, 0, stream>>>(w_red, wtf);
    dw_kern<<<dim3(128, BB), 256, 0, stream>>>(x, w_in, b_in, wtf, b_red,
                                               w_span, b_span, kern, x1g);
    invol_dw<<<dim3(CC, BB), 256, 0, stream>>>(x1g, kern, w_out, b_out, out);
}

// Round 14
// 137.746 us; speedup vs baseline: 2.5439x; 1.0187x over previous
//
#include <hip/hip_runtime.h>

#define BB 8
#define CC 256
#define HH 64
#define WW 64
#define RED 64
#define HW 4096   // HH*WW
#define AST 72    // xs bf16 row stride ([px][c] layout, 16B-aligned rows)
#define LSH 72    // bf16 LDS row stride (x1 / res planes in invol_dw)

typedef __attribute__((ext_vector_type(8))) short s8v;   // 8 bf16 (4 VGPRs)
typedef __attribute__((ext_vector_type(4))) float f4v;   // MFMA accumulator

__device__ __forceinline__ unsigned short f2bf(float f) {  // RNE f32->bf16
    unsigned u = __float_as_uint(f);
    u += 0x7fff + ((u >> 16) & 1);
    return (unsigned short)(u >> 16);
}
__device__ __forceinline__ float b2f(unsigned short u) {   // bf16->f32
    return __uint_as_float(((unsigned)u) << 16);
}

// ---- build w_red in B-fragment order (bf16) ----
// wtf[e], e = ((kbg*4 + nt)*64 + lane)*8 + j  holds  B[k][n] = w_red[o=n][c=k]
// with n = nt*16 + (lane&15), k = kbg*32 + (lane>>4)*8 + j.  32 KB, L2-resident.
// [R12 lesson: building these frags in dw_kern registers spills -- keep.]
__global__ __launch_bounds__(256) void build_wtf(const float* __restrict__ w_red,
                                                 unsigned short* __restrict__ wtf) {
    int e = blockIdx.x * 256 + threadIdx.x;      // 64 blocks -> 16384
    int j = e & 7, l = (e >> 3) & 63, nt = (e >> 9) & 3, kbg = e >> 11;
    int o = nt * 16 + (l & 15);
    int c = kbg * 32 + ((l >> 4) & 3) * 8 + j;
    wtf[e] = f2bf(w_red[o * CC + c]);
}

// ---- fused dwconv1 + involution-kernel-generation (half-row blocks) ----
// R4-EXACT body (best measured: 138.1us total).  256 threads / 4 waves,
// grid (128,8) -> 4 blocks/CU.  [R7: 8 blk/CU regressed; R12: register
// B-frags spill; R10: device-scope sync costs ~200us; R1: coop launch
// fails under capture.  Two-barrier k-loop -- do not re-pipeline.]
__global__ __launch_bounds__(256, 4) void dw_kern(const float* __restrict__ x,
                                                  const float* __restrict__ w_in,
                                                  const float* __restrict__ b_in,
                                                  const unsigned short* __restrict__ wtf,
                                                  const float* __restrict__ b_red,
                                                  const float* __restrict__ w_span,  // [9][64]
                                                  const float* __restrict__ b_span,
                                                  float* __restrict__ kern,
                                                  unsigned short* __restrict__ x1g) {
    alignas(16) __shared__ char smem[8448 + 12288];      // 20.25 KB
    unsigned short* xs = (unsigned short*)smem;          // [32px][AST] bf16 (4.6 KB)
    float* r_lds = (float*)smem;                         // [64o][33] f32, aliases xs (dead)
    float* wl    = (float*)(smem + 8448);                // [256c][12] w_in+b_in staging
    float* part  = (float*)(smem + 8448);                // [8og][9][32px], aliases wl (dead)

    const int t    = threadIdx.x;
    const int bx   = blockIdx.x;
    const int band = bx & 7;                     // XCD band swizzle
    const int idx  = bx >> 3;                    // 0..15
    const int h    = band * 8 + (idx >> 1);      // 8 consecutive h per XCD band
    const int wh   = idx & 1;                    // which 32-px half of the row
    const int b    = blockIdx.y;
    const int l  = t & 63;                       // lane
    const int wv = t >> 6;                       // wave 0..3
    const int mt = wv & 1, nh = wv >> 1;
    const int m0 = mt << 4;
    // phase-A mapping: 8 col-quads x 32 channel-rows
    const int q  = t & 7;
    const int pl = q << 2;                       // local px 0..28
    const int wg = (wh << 5) | pl;               // global w 0..60
    const int cr = t >> 3;                       // 0..31

    // stage w_in [256][9] + b_in [256] -> wl[c*12 + {0..8, 9}] (one-time)
    #pragma unroll
    for (int j = 0; j < 9; j++) {
        int i = j * 256 + t;                     // coalesced read of 2304 floats
        wl[(i / 9) * 12 + (i % 9)] = w_in[i];
    }
    wl[t * 12 + 9] = b_in[t];

    float4 pv[2][3]; float plf[2][3], prt[2][3]; // x-row prefetch regs

    auto loadX = [&](int c0) {
        #pragma unroll
        for (int s = 0; s < 2; s++) {
            const int cc = c0 + s * 32 + cr;
            const float* xp = x + ((size_t)(b * CC + cc)) * HW;
            #pragma unroll
            for (int ky = 0; ky < 3; ky++) {
                int hh = h + ky - 1;
                if (hh < 0 || hh >= HH) {        // block-uniform branch
                    pv[s][ky] = make_float4(0.f, 0.f, 0.f, 0.f);
                    plf[s][ky] = 0.f; prt[s][ky] = 0.f;
                    continue;
                }
                const float* row = xp + hh * WW + wg;
                pv[s][ky]  = *(const float4*)row;
                plf[s][ky] = (wg > 0)      ? row[-1] : 0.f;
                prt[s][ky] = (wg + 4 < WW) ? row[4]  : 0.f;
            }
        }
    };
    auto computeA = [&](int c0) {                // dwconv from regs -> bf16 xs + x1g
        #pragma unroll
        for (int s = 0; s < 2; s++) {
            const int cl = s * 32 + cr;
            const int cc = c0 + cl;
            const float* wp = wl + cc * 12;      // weights from LDS (staged once)
            float4 wa = *(const float4*)wp;      // w0..w3
            float4 wb = *(const float4*)(wp + 4);// w4..w7
            float2 wc = *(const float2*)(wp + 8);// w8, bias
            float4 a4 = make_float4(wc.y, wc.y, wc.y, wc.y);
            const float kw[9] = {wa.x, wa.y, wa.z, wa.w, wb.x, wb.y, wb.z, wb.w, wc.x};
            #pragma unroll
            for (int ky = 0; ky < 3; ky++) {
                float4 v = pv[s][ky];
                float lf = plf[s][ky], rt = prt[s][ky];
                float k0 = kw[ky * 3 + 0], k1 = kw[ky * 3 + 1], k2 = kw[ky * 3 + 2];
                a4.x = fmaf(k0, lf,  a4.x); a4.y = fmaf(k0, v.x, a4.y);
                a4.z = fmaf(k0, v.y, a4.z); a4.w = fmaf(k0, v.z, a4.w);
                a4.x = fmaf(k1, v.x, a4.x); a4.y = fmaf(k1, v.y, a4.y);
                a4.z = fmaf(k1, v.z, a4.z); a4.w = fmaf(k1, v.w, a4.w);
                a4.x = fmaf(k2, v.y, a4.x); a4.y = fmaf(k2, v.z, a4.y);
                a4.z = fmaf(k2, v.w, a4.z); a4.w = fmaf(k2, rt,  a4.w);
            }
            ushort4 pk;
            pk.x = f2bf(a4.x); pk.y = f2bf(a4.y);
            pk.z = f2bf(a4.z); pk.w = f2bf(a4.w);
            xs[(pl + 0) * AST + cl] = pk.x;      // [px][c] for A-frag reads
            xs[(pl + 1) * AST + cl] = pk.y;
            xs[(pl + 2) * AST + cl] = pk.z;
            xs[(pl + 3) * AST + cl] = pk.w;
            // bf16 x1 handoff for kernel 2
            *(ushort4*)(x1g + ((size_t)(b * CC + cc)) * HW + h * WW + wg) = pk;
        }
    };

    s8v bfr[2][2];                               // B-frags [kb][ntl] for current chunk
    auto loadB = [&](int k) {
        #pragma unroll
        for (int kb = 0; kb < 2; kb++)
            #pragma unroll
            for (int ntl = 0; ntl < 2; ntl++) {
                int nt = (nh << 1) + ntl;
                int kbg = (k << 1) + kb;
                bfr[kb][ntl] = *(const s8v*)(wtf + (((kbg * 4 + nt) * 64 + l) << 3));
            }
    };

    f4v acc[2] = {{0.f, 0.f, 0.f, 0.f}, {0.f, 0.f, 0.f, 0.f}};

    loadX(0); loadB(0);
    __syncthreads();                             // wl staged before computeA reads it
    for (int k = 0; k < 4; k++) {
        computeA(k << 6);                        // regs -> xs (bf16) + x1g
        if (k < 3) loadX((k + 1) << 6);          // VMEM issue for next chunk
        __syncthreads();
        // phase B: 2 A-frag ds_read_b128 + 4 MFMA per wave
        #pragma unroll
        for (int kb = 0; kb < 2; kb++) {
            const unsigned short* ap =
                xs + (m0 + (l & 15)) * AST + (kb << 5) + ((l >> 4) & 3) * 8;
            s8v av = *(const s8v*)ap;
            #pragma unroll
            for (int ntl = 0; ntl < 2; ntl++)
                acc[ntl] = __builtin_amdgcn_mfma_f32_16x16x32_bf16(
                    av, bfr[kb][ntl], acc[ntl], 0, 0, 0);
        }
        if (k < 3) loadB(k + 1);
        __syncthreads();                         // xs consumed; safe to overwrite
    }

    // C-frags -> r_lds[o][33] (aliases dead xs); D row = px, col = o
    #pragma unroll
    for (int ntl = 0; ntl < 2; ntl++) {
        int o = ((nh << 1) + ntl) * 16 + (l & 15);
        int pxr = m0 + ((l >> 4) & 3) * 4;       // row = (lane>>4)*4 + i
        #pragma unroll
        for (int i = 0; i < 4; i++)
            r_lds[o * 33 + pxr + i] = acc[ntl][i];
    }
    __syncthreads();

    // epilogue: relu + span contraction; og = t>>5 (8 o-groups of 8)
    const int px = t & 31;
    const int og = t >> 5;
    const int o0 = og << 3;
    float kk[9];
    #pragma unroll
    for (int j = 0; j < 9; j++) kk[j] = 0.f;
    #pragma unroll
    for (int i = 0; i < 8; i++) {
        float r = fmaxf(r_lds[(o0 + i) * 33 + px] + b_red[o0 + i], 0.f);
        #pragma unroll
        for (int j = 0; j < 9; j++) kk[j] = fmaf(w_span[j * RED + o0 + i], r, kk[j]);
    }
    __syncthreads();                             // wl dead -> part may overwrite
    #pragma unroll
    for (int j = 0; j < 9; j++) part[(og * 9 + j) * 32 + px] = kk[j];
    __syncthreads();

    // cross-o-group reduction: thread (px, jj) sums 8 partials for kern[jj]
    float* kp = kern + (size_t)b * 9 * HW + h * WW + (wh << 5) + px;
    const int jj = t >> 5;                       // 0..7
    {
        float s = b_span[jj];
        #pragma unroll
        for (int g = 0; g < 8; g++) s += part[(g * 9 + jj) * 32 + px];
        kp[jj * HW] = s;
    }
    if (t < 32) {                                // j = 8 by lanes 0..31
        float s = b_span[8];
        #pragma unroll
        for (int g = 0; g < 8; g++) s += part[(g * 9 + 8) * 32 + px];
        kp[8 * HW] = s;
    }
}

// ---- involution-apply + dwconv2, TWO c-planes per block ----
// R14: kern depends only on b, not c -- so one block handles (c, c+1) and
// each kern float4 load feeds BOTH planes' FMAs.  This halves the dominant
// VMEM term (36 float4 kern gathers/thread -> 18 per plane-equivalent;
// total per-thread VMEM 84 -> 48 per plane-pair).  R7/R13 falsified the
// occupancy lever twice; instruction-count reduction is what's left.
// Involution accs held in regs (8 float4 = 32 VGPR) across the i-loop;
// bf16 res written into the DEAD x1 LDS after a barrier (aliasing).
// LDS 18.4 KB; launch_bounds(256,4) -> VGPR<=128, 4 blocks/CU; grid
// (128,8)=1024 = exactly one round.  Arithmetic identical to R13's
// verified bf16-res version -> absmax unchanged.
__global__ __launch_bounds__(256, 4) void invol_dw(const unsigned short* __restrict__ x1g,
                                                   const float* __restrict__ kern,
                                                   const float* __restrict__ w_out,
                                                   const float* __restrict__ b_out,
                                                   float* __restrict__ out) {
    __shared__ unsigned short pln[2][HH * LSH];  // x1 planes, later res planes (18.4 KB)
    const int t  = threadIdx.x;
    const int q  = t & 15;
    const int w0 = q << 2;
    const int r  = t >> 4;                       // 0..15
    const int c0 = blockIdx.x << 1, b = blockIdx.y;

    // stage both x1 planes: 2 x 4096 bf16, fully contiguous
    {
        const int hl = t >> 2;                   // 0..63
        const int wl2 = (t & 3) << 4;            // 0,16,32,48
        #pragma unroll
        for (int p = 0; p < 2; p++) {
            const unsigned short* xp = x1g + ((size_t)(b * CC + c0 + p)) * HW;
            *(s8v*)&pln[p][hl * LSH + wl2]     = *(const s8v*)(xp + hl * WW + wl2);
            *(s8v*)&pln[p][hl * LSH + wl2 + 8] = *(const s8v*)(xp + hl * WW + wl2 + 8);
        }
    }
    __syncthreads();

    // involution, both planes, kern loads shared; accs in registers
    const float* kp = kern + (size_t)b * 9 * HW;
    float4 a0[4], a1[4];
    #pragma unroll
    for (int i = 0; i < 4; i++) {
        a0[i] = make_float4(0.f, 0.f, 0.f, 0.f);
        a1[i] = make_float4(0.f, 0.f, 0.f, 0.f);
    }
    #pragma unroll
    for (int i = 0; i < 4; i++) {
        int h  = r + (i << 4);
        int hw = h * WW + w0;
        #pragma unroll
        for (int ky = 0; ky < 3; ky++) {
            int hh = h + ky - 1;
            if (hh < 0 || hh >= HH) continue;    // zero patch
            float4 k0 = *(const float4*)(kp + (ky * 3 + 0) * HW + hw);
            float4 k1 = *(const float4*)(kp + (ky * 3 + 1) * HW + hw);
            float4 k2 = *(const float4*)(kp + (ky * 3 + 2) * HW + hw);
            #pragma unroll
            for (int p = 0; p < 2; p++) {        // static after unroll
                const unsigned short* row = &pln[p][hh * LSH + w0];
                float vx = b2f(row[0]), vy = b2f(row[1]);
                float vz = b2f(row[2]), vw = b2f(row[3]);
                float lf = (w0 > 0)      ? b2f(row[-1]) : 0.f;
                float rt = (w0 + 4 < WW) ? b2f(row[4])  : 0.f;
                float4& a = p ? a1[i] : a0[i];
                a.x = fmaf(k0.x, lf, a.x); a.y = fmaf(k0.y, vx, a.y);
                a.z = fmaf(k0.z, vy, a.z); a.w = fmaf(k0.w, vz, a.w);
                a.x = fmaf(k1.x, vx, a.x); a.y = fmaf(k1.y, vy, a.y);
                a.z = fmaf(k1.z, vz, a.z); a.w = fmaf(k1.w, vw, a.w);
                a.x = fmaf(k2.x, vy, a.x); a.y = fmaf(k2.y, vz, a.y);
                a.z = fmaf(k2.z, vw, a.z); a.w = fmaf(k2.w, rt, a.w);
            }
        }
    }
    __syncthreads();                             // all x1 reads complete

    // write bf16 res into the dead x1 space
    #pragma unroll
    for (int i = 0; i < 4; i++) {
        int h = r + (i << 4);
        ushort4 pk;
        pk.x = f2bf(a0[i].x); pk.y = f2bf(a0[i].y);
        pk.z = f2bf(a0[i].z); pk.w = f2bf(a0[i].w);
        *(ushort4*)&pln[0][h * LSH + w0] = pk;
        pk.x = f2bf(a1[i].x); pk.y = f2bf(a1[i].y);
        pk.z = f2bf(a1[i].z); pk.w = f2bf(a1[i].w);
        *(ushort4*)&pln[1][h * LSH + w0] = pk;
    }
    __syncthreads();                             // res visible to all threads

    // dwconv2, both planes, from bf16 res
    #pragma unroll
    for (int p = 0; p < 2; p++) {
        const float* wp = w_out + (c0 + p) * 9;  // block-uniform -> s_load
        const float bb = b_out[c0 + p];
        float* op = out + ((size_t)(b * CC + c0 + p)) * HW;
        #pragma unroll
        for (int i = 0; i < 4; i++) {
            int h = r + (i << 4);
            float4 acc = make_float4(bb, bb, bb, bb);
            #pragma unroll
            for (int ky = 0; ky < 3; ky++) {
                int hh = h + ky - 1;
                if (hh < 0 || hh >= HH) continue;
                const unsigned short* row = &pln[p][hh * LSH + w0];
                float vx = b2f(row[0]), vy = b2f(row[1]);
                float vz = b2f(row[2]), vw = b2f(row[3]);
                float lf = (w0 > 0)      ? b2f(row[-1]) : 0.f;
                float rt = (w0 + 4 < WW) ? b2f(row[4])  : 0.f;
                float k0 = wp[ky * 3 + 0], k1 = wp[ky * 3 + 1], k2 = wp[ky * 3 + 2];
                acc.x = fmaf(k0, lf, acc.x); acc.y = fmaf(k0, vx, acc.y);
                acc.z = fmaf(k0, vy, acc.z); acc.w = fmaf(k0, vz, acc.w);
                acc.x = fmaf(k1, vx, acc.x); acc.y = fmaf(k1, vy, acc.y);
                acc.z = fmaf(k1, vz, acc.z); acc.w = fmaf(k1, vw, acc.w);
                acc.x = fmaf(k2, vy, acc.x); acc.y = fmaf(k2, vz, acc.y);
                acc.z = fmaf(k2, vw, acc.z); acc.w = fmaf(k2, rt, acc.w);
            }
            *(float4*)(op + h * WW + w0) = acc;
        }
    }
}

extern "C" void kernel_launch(void* const* d_in, const int* in_sizes, int n_in,
                              void* d_out, int out_size, void* d_ws, size_t ws_size,
                              hipStream_t stream) {
    const float* x      = (const float*)d_in[0];
    const float* w_in   = (const float*)d_in[1];
    const float* b_in   = (const float*)d_in[2];
    const float* w_red  = (const float*)d_in[3];
    const float* b_red  = (const float*)d_in[4];
    const float* w_span = (const float*)d_in[5];
    const float* b_span = (const float*)d_in[6];
    const float* w_out  = (const float*)d_in[7];
    const float* b_out  = (const float*)d_in[8];
    float* out = (float*)d_out;

    float* kern = (float*)d_ws;                              // 1.18 MB
    unsigned short* x1g = (unsigned short*)(kern + (size_t)BB * 9 * HW); // 16.8 MB bf16
    unsigned short* wtf = x1g + (size_t)BB * CC * HW;        // 32 KB bf16

    build_wtf<<<64, 256, 0, stream>>>(w_red, wtf);
    dw_kern<<<dim3(128, BB), 256, 0, stream>>>(x, w_in, b_in, wtf, b_red,
                                               w_span, b_span, kern, x1g);
    invol_dw<<<dim3(CC / 2, BB), 256, 0, stream>>>(x1g, kern, w_out, b_out, out);
}